// Round 1
// baseline (11082.062 us; speedup 1.0000x reference)
//
#include <hip/hip_runtime.h>
#include <math.h>

#define B_ 64
#define T_ 2048
#define D_ 512
#define BT_ (B_ * T_)   // 131072

// ---------------------------------------------------------------------------
// Kernel 1: weight prep (transpose to k-major for coalesced GEMM/GEMV reads)
//   Wcat[k][j], j<512:  tau_w[j*1024 + k]      (x -> gate half)
//              j>=512:  mem_w[(j-512)*512 + k] (x -> mem)
//   WTh[k][d]        :  tau_w[d*1024 + 512+k]  (tau -> gate recurrent half)
// ---------------------------------------------------------------------------
__global__ void prep_weights(const float* __restrict__ tau_w,
                             const float* __restrict__ mem_w,
                             float* __restrict__ Wcat,
                             float* __restrict__ WTh) {
    int idx = blockIdx.x * 256 + threadIdx.x;   // 0 .. 524287
    {
        int k = idx >> 10, j = idx & 1023;
        float v = (j < 512) ? tau_w[j * 1024 + k] : mem_w[(j - 512) * 512 + k];
        Wcat[idx] = v;
    }
    if (idx < 512 * 512) {
        int k = idx >> 9, d = idx & 511;
        WTh[idx] = tau_w[d * 1024 + 512 + k];
    }
}

// ---------------------------------------------------------------------------
// Kernel 2: f32 GEMM  C[131072][1024] = X[131072][512] @ Wcat[512][1024] + bias
//   cols 0..511   -> Aout (spikes region of d_out, overwritten later by scan)
//   cols 512..1023-> Mout (workspace)
// 128x128 tile, 256 threads, 8x8 microtile, BK=16.
// ---------------------------------------------------------------------------
__global__ __launch_bounds__(256, 2)
void gemm_xw(const float* __restrict__ X, const float* __restrict__ Wc,
             const float* __restrict__ tau_b, const float* __restrict__ mem_b,
             float* __restrict__ Aout, float* __restrict__ Mout) {
    __shared__ __align__(16) float As[16][128];  // [k][m]
    __shared__ __align__(16) float Bs[16][128];  // [k][n]
    const int bn = blockIdx.x;          // 0..7
    const int bm = blockIdx.y;          // 0..1023
    const int tid = threadIdx.x;
    const int tm = (tid >> 4) << 3;
    const int tn = (tid & 15) << 3;
    const int m0 = bm * 128, n0 = bn * 128;

    const float4* X4 = (const float4*)X;
    const float4* Wc4 = (const float4*)Wc;

    float acc[8][8];
#pragma unroll
    for (int i = 0; i < 8; i++)
#pragma unroll
        for (int j = 0; j < 8; j++) acc[i][j] = 0.0f;

    const int ar = tid >> 1;              // 0..127 row in tile
    const int ac2 = (tid & 1) * 2;        // float4 col 0 or 2
    const int bkr = tid >> 4;             // 0..15
    const int bc = (tid & 15) * 2;        // float4 col 0..30

    for (int kt = 0; kt < 512; kt += 16) {
        float4 av0 = X4[(m0 + ar) * 128 + (kt >> 2) + ac2];
        float4 av1 = X4[(m0 + ar) * 128 + (kt >> 2) + ac2 + 1];
        float4 bv0 = Wc4[(kt + bkr) * 256 + bn * 32 + bc];
        float4 bv1 = Wc4[(kt + bkr) * 256 + bn * 32 + bc + 1];
        __syncthreads();   // protect previous iteration's reads
        As[ac2 * 4 + 0][ar] = av0.x;
        As[ac2 * 4 + 1][ar] = av0.y;
        As[ac2 * 4 + 2][ar] = av0.z;
        As[ac2 * 4 + 3][ar] = av0.w;
        As[ac2 * 4 + 4][ar] = av1.x;
        As[ac2 * 4 + 5][ar] = av1.y;
        As[ac2 * 4 + 6][ar] = av1.z;
        As[ac2 * 4 + 7][ar] = av1.w;
        *(float4*)&Bs[bkr][bc * 4] = bv0;
        *(float4*)&Bs[bkr][bc * 4 + 4] = bv1;
        __syncthreads();
#pragma unroll
        for (int kk = 0; kk < 16; kk++) {
            float4 a0 = *(const float4*)&As[kk][tm];
            float4 a1 = *(const float4*)&As[kk][tm + 4];
            float4 b0 = *(const float4*)&Bs[kk][tn];
            float4 b1 = *(const float4*)&Bs[kk][tn + 4];
            float av[8] = {a0.x, a0.y, a0.z, a0.w, a1.x, a1.y, a1.z, a1.w};
            float bv[8] = {b0.x, b0.y, b0.z, b0.w, b1.x, b1.y, b1.z, b1.w};
#pragma unroll
            for (int i = 0; i < 8; i++)
#pragma unroll
                for (int j = 0; j < 8; j++)
                    acc[i][j] = fmaf(av[i], bv[j], acc[i][j]);
        }
    }

    const bool isA = (bn < 4);
    float* Cout = isA ? Aout : Mout;
    const float* bias = isA ? tau_b : mem_b;
    const int ncol0 = (isA ? n0 : n0 - 512) + tn;
    float bj[8];
#pragma unroll
    for (int j = 0; j < 8; j++) bj[j] = bias[ncol0 + j];
#pragma unroll
    for (int i = 0; i < 8; i++) {
        size_t off = (size_t)(m0 + tm + i) * 512 + ncol0;
        float4 o0, o1;
        o0.x = acc[i][0] + bj[0]; o0.y = acc[i][1] + bj[1];
        o0.z = acc[i][2] + bj[2]; o0.w = acc[i][3] + bj[3];
        o1.x = acc[i][4] + bj[4]; o1.y = acc[i][5] + bj[5];
        o1.z = acc[i][6] + bj[6]; o1.w = acc[i][7] + bj[7];
        *(float4*)&Cout[off] = o0;
        *(float4*)&Cout[off + 4] = o1;
    }
}

// ---------------------------------------------------------------------------
// Kernel 3: sequential scan. One block per batch element (64 blocks, 512 thr).
// Per step: tau_mm[d] = sum_k tau[k]*WTh[k][d]  (512x512 GEMV),
// then elementwise gate/alpha/v/spike. Weights: 48 rows/quadrant in VGPRs,
// 16 rows/quadrant in LDS, 64 rows/quadrant streamed from L2.
// ---------------------------------------------------------------------------
#define KRR 48   // register-resident float4 rows per k-group
#define KLL 16   // LDS-resident rows per k-group

__device__ __forceinline__ float4 f4fma(float t, float4 w, float4 a) {
    a.x = fmaf(t, w.x, a.x);
    a.y = fmaf(t, w.y, a.y);
    a.z = fmaf(t, w.z, a.z);
    a.w = fmaf(t, w.w, a.w);
    return a;
}

__global__ __launch_bounds__(512, 2)
void scan_kernel(const float* __restrict__ WTh,
                 const float* __restrict__ Mm,
                 const float* __restrict__ log_thresh,
                 float* AmOut /* A in / spikes out, same region */,
                 float* OutTail /* d_out base for tau/v tails */) {
    __shared__ __align__(16) float tau_s[512];
    __shared__ __align__(16) float4 part4[4][128];
    __shared__ __align__(16) float4 wlds4[4][KLL][128];

    const int b = blockIdx.x;
    const int tid = threadIdx.x;
    const int kg = tid >> 7;      // 0..3 k-quadrant
    const int d4 = tid & 127;     // output float4 index
    const int k0 = kg << 7;       // quadrant base row
    const float4* W4 = (const float4*)WTh;

    // preload register-resident weights (rows k0 .. k0+KRR-1, cols 4*d4..+3)
    float4 wreg[KRR];
#pragma unroll
    for (int r = 0; r < KRR; r++) wreg[r] = W4[(k0 + r) * 128 + d4];
    // LDS-resident rows k0+KRR .. k0+KRR+KLL-1 (each element used by 1 thread)
#pragma unroll
    for (int l = 0; l < KLL; l++) wlds4[kg][l][d4] = W4[(k0 + KRR + l) * 128 + d4];

    tau_s[tid] = 1.0f;                    // initial carry tau = ones
    float v = 0.0f;                       // initial carry v = zeros
    const float thr = 1.0f / (1.0f + expf(-log_thresh[tid]));
    __syncthreads();

    size_t base = (size_t)b * T_ * D_ + tid;
    const float4* tau4 = (const float4*)tau_s;
    const int tq0 = kg * 32;

    for (int t = 0; t < T_; t++) {
        // prefetch this step's A (gate x-part + bias) and M (mem + bias)
        float a_in = AmOut[base];
        float m_in = Mm[base];

        float4 acc = make_float4(0.f, 0.f, 0.f, 0.f);
        // register-resident rows
#pragma unroll
        for (int q = 0; q < KRR / 4; q++) {
            float4 tv = tau4[tq0 + q];
            acc = f4fma(tv.x, wreg[4 * q + 0], acc);
            acc = f4fma(tv.y, wreg[4 * q + 1], acc);
            acc = f4fma(tv.z, wreg[4 * q + 2], acc);
            acc = f4fma(tv.w, wreg[4 * q + 3], acc);
        }
        // LDS-resident rows
#pragma unroll
        for (int q = 0; q < KLL / 4; q++) {
            float4 tv = tau4[tq0 + KRR / 4 + q];
            acc = f4fma(tv.x, wlds4[kg][4 * q + 0][d4], acc);
            acc = f4fma(tv.y, wlds4[kg][4 * q + 1][d4], acc);
            acc = f4fma(tv.z, wlds4[kg][4 * q + 2][d4], acc);
            acc = f4fma(tv.w, wlds4[kg][4 * q + 3][d4], acc);
        }
        // streamed rows (L2-resident working set, shared by blocks on the XCD)
#pragma unroll 2
        for (int q = (KRR + KLL) / 4; q < 32; q++) {
            float4 tv = tau4[tq0 + q];
            int krow = k0 + 4 * q;
            float4 w0 = W4[(krow + 0) * 128 + d4];
            float4 w1 = W4[(krow + 1) * 128 + d4];
            float4 w2 = W4[(krow + 2) * 128 + d4];
            float4 w3 = W4[(krow + 3) * 128 + d4];
            acc = f4fma(tv.x, w0, acc);
            acc = f4fma(tv.y, w1, acc);
            acc = f4fma(tv.z, w2, acc);
            acc = f4fma(tv.w, w3, acc);
        }
        part4[kg][d4] = acc;
        __syncthreads();

        // epilogue: thread tid owns output channel d = tid
        const float* pp = (const float*)part4;
        float sum = ((pp[tid] + pp[512 + tid]) + pp[1024 + tid]) + pp[1536 + tid];
        float pre = sum + a_in;
        float tau = 1.0f / (1.0f + expf(-pre));
        float alpha = expf(-1.0f / (tau + 1e-6f));
        v = alpha * v + (1.0f - alpha) * m_in;
        float s = (v >= thr) ? 1.0f : 0.0f;
        AmOut[base] = s;          // overwrite A slot with spike
        v = v * (1.0f - s);
        tau_s[tid] = tau;
        base += D_;
        __syncthreads();          // tau_s/part4 ready for next step
    }

    // final carries: tau then v
    OutTail[(size_t)BT_ * D_ + (size_t)b * D_ + tid] = tau_s[tid];
    OutTail[(size_t)BT_ * D_ + (size_t)B_ * D_ + (size_t)b * D_ + tid] = v;
}

// ---------------------------------------------------------------------------
extern "C" void kernel_launch(void* const* d_in, const int* in_sizes, int n_in,
                              void* d_out, int out_size, void* d_ws, size_t ws_size,
                              hipStream_t stream) {
    (void)in_sizes; (void)n_in; (void)out_size; (void)ws_size;
    const float* x          = (const float*)d_in[0];
    const float* tau_w      = (const float*)d_in[1];
    const float* tau_b      = (const float*)d_in[2];
    const float* mem_w      = (const float*)d_in[3];
    const float* mem_b      = (const float*)d_in[4];
    const float* log_thresh = (const float*)d_in[5];
    float* out = (float*)d_out;

    // workspace layout
    float* Wcat = (float*)d_ws;            // 512*1024
    float* WTh  = Wcat + 512 * 1024;       // 512*512
    float* Mout = WTh + 512 * 512;         // 131072*512

    float* Aout = out;                     // spikes region doubles as A buffer

    prep_weights<<<2048, 256, 0, stream>>>(tau_w, mem_w, Wcat, WTh);
    gemm_xw<<<dim3(8, 1024), 256, 0, stream>>>(x, Wcat, tau_b, mem_b, Aout, Mout);
    scan_kernel<<<64, 512, 0, stream>>>(WTh, Mout, log_thresh, Aout, out);
}